// Round 8
// baseline (642.337 us; speedup 1.0000x reference)
//
#include <hip/hip_runtime.h>

#define EPSILON 0.001f
#define NSUP 601
#define BLOCK_THREADS 256

typedef float v4f __attribute__((ext_vector_type(4)));

// ---------------------------------------------------------------------------
// Two-step: (1) hipMemsetAsync zeroes the 630 MB output via AMD's
// __amd_rocclr_fillBufferAligned — the kernel measured at 6.2-6.3 TB/s on
// this part every round (my hand-written fills appear to sustain less).
// (2) scatter kernel writes the two-hot values as FULL 64-byte lines:
// per row, 8 lanes store the 32-dword (128 B, 64B-aligned) window containing
// both targets. Fully-covered lines don't read-allocate in L2, so there is
// no RMW fetch even though memset evicted them. Extra traffic: 33.5 MB.
//
// Window-safety: window = [gl & ~15, +32 dwords). It stays inside the row iff
// a0 >= row_start && a0+32 <= row_end (true for all |t| < 284; for normal
// inputs always). Otherwise fall back to two scalar dword stores (correct,
// rare-to-never). Collision at the top clamp (lower==upper==600): reference's
// upper write wins; here the gu test is applied after gl, and pl_store is
// substituted with p_high, so any order gives p_high.
// ---------------------------------------------------------------------------
__global__ __launch_bounds__(BLOCK_THREADS)
void twohot_scatter_lines(const float* __restrict__ x,
                          const float* __restrict__ supports,
                          float* __restrict__ out, int nrows) {
    const int tid = blockIdx.x * BLOCK_THREADS + threadIdx.x;
    const int row = tid >> 3;          // 8 lanes cooperate per row
    const int sub = tid & 7;
    if (row >= nrows) return;

    const float v = x[row];            // 8 lanes same address -> broadcast
    const float s = (v > 0.f) ? 1.f : ((v < 0.f) ? -1.f : 0.f);
    const float t = s * (sqrtf(fabsf(v) + 1.f) - 1.f + EPSILON * v);

    // supports = linspace(-300,300,601), unit spacing:
    // searchsorted(right)-1 == floor(t)+300, clamped.
    int idx = (int)floorf(t) + 300;
    const int lower = idx < 0 ? 0 : (idx > NSUP - 1 ? NSUP - 1 : idx);
    const int upper = (lower + 1 > NSUP - 1) ? NSUP - 1 : lower + 1;

    const float ls = supports[lower];
    const float us = supports[upper];
    const float p_low = (us - t) / (us - ls);      // denom == 1.0 in-range
    const float p_high = 1.f - p_low;
    const float pl_store = (lower == upper) ? p_high : p_low;

    const long long row_start = (long long)row * NSUP;
    const long long row_end = row_start + NSUP;
    const long long gl = row_start + lower;
    const long long gu = row_start + upper;
    const long long a0 = gl & ~15LL;               // 64B-aligned window start

    if (a0 >= row_start && a0 + 32 <= row_end) {
        // fast path: two fully-covered 64B lines, 8 lanes x dwordx4
        const long long g0 = a0 + (long long)sub * 4;
        v4f val;
        #pragma unroll
        for (int e = 0; e < 4; ++e) {
            const long long g = g0 + e;
            float f = 0.f;
            if (g == gl) f = pl_store;
            if (g == gu) f = p_high;   // applied last -> wins on collision
            val[e] = f;
        }
        *(v4f*)(out + g0) = val;
    } else if (sub == 0) {
        // rare fallback (window would cross a row boundary): scalar stores
        out[gl] = pl_store;
        out[gu] = p_high;              // same value on collision -> order-free
    }
}

extern "C" void kernel_launch(void* const* d_in, const int* in_sizes, int n_in,
                              void* d_out, int out_size, void* d_ws, size_t ws_size,
                              hipStream_t stream) {
    const float* tv = (const float*)d_in[0];
    const float* supports = (const float*)d_in[1];
    float* out = (float*)d_out;

    // Bulk zero at AMD-fill-kernel rate (graph-capturable memset node).
    hipMemsetAsync(d_out, 0, (size_t)out_size * sizeof(float), stream);

    const int nrows = in_sizes[0];                       // 262144
    const int nthreads = nrows * 8;                      // 8 lanes per row
    const int nblocks = (nthreads + BLOCK_THREADS - 1) / BLOCK_THREADS;  // 8192
    twohot_scatter_lines<<<nblocks, BLOCK_THREADS, 0, stream>>>(
        tv, supports, out, nrows);
}

// Round 9
// 631.464 us; speedup vs baseline: 1.0172x; 1.0172x over previous
//
#include <hip/hip_runtime.h>

#define EPSILON 0.001f
#define NSUP 601
#define BLOCK_THREADS 256
#define ROWS_PER_WAVE 16
#define F4_PER_WAVE 2404   // 16*601/4 — exact; span starts are 64B aligned (16*601*4 = 601*64)

typedef float v4f __attribute__((ext_vector_type(4)));

// ---------------------------------------------------------------------------
// FINAL (best measured: 633.4 us, R7). One wave per 16 consecutive rows
// (9616 floats == 2404 float4, span start 64B-aligned).
// Phase 1: branch-free dense dwordx4 zero-fill of the span — same pattern as
//          __amd_rocclr_fillBufferAligned. (No nt flag: R6 measured nt -33%.)
// Phase 2: __threadfence_block (per-wave vmcnt drain, no barrier), then 32
//          scattered dword stores (2 per row) into the wave's own span.
// Params: every lane computes t/lower/upper/p for row 16w+(lane&15) —
//          redundant x4 but divergence-free; valid registers in all lanes
//          for the __shfl gather in phase 2.
// Collision (top clamp, lower==upper==600): reference's upper write wins;
//          the lower-writing lane substitutes p_high, so order-independent.
//
// Roofline evidence (R1-R8): dur_us dominated by mandatory HBM stores
// (2.52 GB harness poison + 630 MB output written exactly once) at 76-79%
// of HBM spec — the measured fill ceiling of this part. R8 (AMD's own fill
// for the bulk + scatter) was 1.4% WORSE; three structures tie within 1.5%.
// ---------------------------------------------------------------------------
__global__ __launch_bounds__(BLOCK_THREADS)
void twohot_span_kernel(const float* __restrict__ x,
                        const float* __restrict__ supports,
                        float* __restrict__ out, int nrows) {
    const int wave_in_blk = threadIdx.x >> 6;
    const int lane = threadIdx.x & 63;
    const int w = blockIdx.x * (BLOCK_THREADS / 64) + wave_in_blk;  // global wave
    const int row0 = w * ROWS_PER_WAVE;
    if (row0 >= nrows) return;

    // --- per-row params, computed by all lanes for row0 + (lane&15) ---
    const int r = lane & 15;
    const float v = x[row0 + r];
    const float s = (v > 0.f) ? 1.f : ((v < 0.f) ? -1.f : 0.f);
    const float t = s * (sqrtf(fabsf(v) + 1.f) - 1.f + EPSILON * v);

    // supports = linspace(-300,300,601), unit spacing:
    // searchsorted(right)-1 == floor(t)+300, clamped.
    int idx = (int)floorf(t) + 300;
    const int lower = idx < 0 ? 0 : (idx > NSUP - 1 ? NSUP - 1 : idx);
    const int upper = (lower + 1 > NSUP - 1) ? NSUP - 1 : lower + 1;

    const float ls = supports[lower];
    const float us = supports[upper];
    const float p_low = (us - t) / (us - ls);       // denom == 1.0 in-range
    const float p_high = 1.f - p_low;
    // value the "lower" scatter lane writes: on collision both lanes write p_high
    const float pl_store = (lower == upper) ? p_high : p_low;

    // --- phase 1: dense zero-fill of the wave's span ---
    v4f* out4 = (v4f*)out + (long long)w * F4_PER_WAVE;
    const v4f z = (v4f)(0.f);
    #pragma unroll
    for (int i = 0; i < F4_PER_WAVE / 64; ++i) {    // 37 full iterations
        out4[i * 64 + lane] = z;
    }
    if (lane < F4_PER_WAVE % 64) {                  // tail: 36 lanes
        out4[(F4_PER_WAVE / 64) * 64 + lane] = z;
    }

    // --- order phase-1 stores before phase-2 stores (same wave, no barrier) ---
    __threadfence_block();

    // --- phase 2: 32 scattered dword stores (2 per row) ---
    if (lane < 2 * ROWS_PER_WAVE) {
        const int src = lane >> 1;                  // source row slot 0..15
        const int sel = lane & 1;                   // 0 -> lower, 1 -> upper
        const int lv = __shfl(lower, src);
        const int uv = __shfl(upper, src);
        const float plv = __shfl(pl_store, src);
        const float phv = __shfl(p_high, src);
        const int col = sel ? uv : lv;
        const float val = sel ? phv : plv;
        out[(long long)(row0 + src) * NSUP + col] = val;
    }
}

extern "C" void kernel_launch(void* const* d_in, const int* in_sizes, int n_in,
                              void* d_out, int out_size, void* d_ws, size_t ws_size,
                              hipStream_t stream) {
    const float* tv = (const float*)d_in[0];
    const float* supports = (const float*)d_in[1];
    float* out = (float*)d_out;

    const int nrows = in_sizes[0];                               // 262144
    const int nwaves = (nrows + ROWS_PER_WAVE - 1) / ROWS_PER_WAVE;  // 16384
    const int nblocks = (nwaves + 3) / 4;                        // 4096
    twohot_span_kernel<<<nblocks, BLOCK_THREADS, 0, stream>>>(tv, supports, out, nrows);
}